// Round 3
// baseline (606.241 us; speedup 1.0000x reference)
//
#include <hip/hip_runtime.h>
#include <hip/hip_fp16.h>

// ---------------- problem constants ----------------
#define TAU_OT   0.005f
#define DELTA_OT 1e-9f
#define LOG2E    1.4426950408889634f
#define C_EPS    0.06931471805599453f   /* 0.1 * ln2 : (1 - eps*K_nat) = 1 - C_EPS*K2 */
#define LM9_2    -29.897352853986263f   /* log2(1e-9) */
#define NEGI     -1.0e30f
#define SCALE_B  14.426950408889634f    /* INV_EPS * LOG2E folded into B norms */

constexpr int BB  = 64;
constexpr int DIM = 768;
constexpr int KP_H = 520;                       // K row pitch in halves (1040 B)
constexpr long KBATCH_H = (long)512 * KP_H;     // 512 rows per batch (no aug storage)

// ---------------- workspace layout (float units) ----------------
constexpr size_t OFF_LENV = 0;        // 64 ints
constexpr size_t OFF_LENT = 64;       // 64 ints
constexpr size_t OFF_LOSS = 128;      // 64 floats (per-batch loss, written not accumulated)
constexpr size_t OFF_KH   = 256;      // half[64 * 512 * 520]

typedef __attribute__((ext_vector_type(8))) short short8;
typedef __attribute__((ext_vector_type(4))) float floatx4;

__device__ inline float ex2(float x){ float r; asm("v_exp_f32 %0, %1" : "=v"(r) : "v"(x)); return r; }
__device__ inline float lg2(float x){ float r; asm("v_log_f32 %0, %1" : "=v"(r) : "v"(x)); return r; }

__device__ inline ushort f2bf(float f) {          // fp32 -> bf16 RNE
    unsigned u = __float_as_uint(f);
    unsigned r = (u + 0x7FFFu + ((u >> 16) & 1u)) >> 16;
    return (ushort)r;
}

// ---------------- mask dtype detection ----------------
__device__ inline int detect_mode(const unsigned char* p) {
    unsigned char b0 = p[0], b1 = p[1];
    if (b0 == 0) return 2;          // float32 (1.0f -> bytes 00 00 80 3F)
    return (b1 != 0) ? 0 : 1;       // 0: u8/bool, 1: int32
}
__device__ inline int read_mask(const unsigned char* p, long idx, int mode) {
    if (mode == 0) return p[idx] != 0;
    if (mode == 1) return p[4*idx] != 0;
    return ((const float*)p)[idx] != 0.0f;
}

// ---------------- lengths: len = sum(mask) (masks are prefix masks) ----------------
__global__ void len_kernel(const unsigned char* vm, const unsigned char* tm,
                           int* lenv, int* lent) {
    int b = blockIdx.x;
    bool isV = (blockIdx.y == 0);
    const unsigned char* p = isV ? vm : tm;
    int mode = detect_mode(p);
    int i = threadIdx.x;                       // 512 threads
    float s = (float)read_mask(p, (long)b*512 + i, mode);
    #pragma unroll
    for (int off = 32; off; off >>= 1) s += __shfl_xor(s, off);
    __shared__ float wsum[8];
    int w = threadIdx.x >> 6, lane = threadIdx.x & 63;
    if (lane == 0) wsum[w] = s;
    __syncthreads();
    if (threadIdx.x == 0) {
        float len = 0.f;
        #pragma unroll
        for (int q = 0; q < 8; ++q) len += wsum[q];
        (isV ? lenv : lent)[b] = (int)(len + 0.5f);
    }
}

// ---------------- bf16 MFMA batched GEMM -> K2 (fp16, log2*10 scale) ----------------
// 128x128 tile, BK=32, 256 threads. Fused row-norms (computed from staged data).
// Tiles fully beyond (len_v, len_t) are skipped entirely.
__global__ __launch_bounds__(256) void gemm_kernel(const float* __restrict__ v,
        const float* __restrict__ t,
        const int* __restrict__ lenvp, const int* __restrict__ lentp,
        __half* __restrict__ K) {
    int bid = blockIdx.x;
    int xcd = bid & 7, kk = bid >> 3;
    int bt   = xcd * 8 + (kk >> 4);
    int tile = kk & 15;
    int m0 = (tile >> 2) * 128, n0 = (tile & 3) * 128;
    if (m0 >= lenvp[bt] || n0 >= lentp[bt]) return;   // fully-masked tile: never read

    __shared__ ushort As[128*40];
    __shared__ ushort Bs[128*40];
    __shared__ float invA[128], invB[128];
    const float* vb = v + (long)bt * 512 * DIM;
    const float* tb = t + (long)bt * 512 * DIM;
    int tid = threadIdx.x;
    int w = tid >> 6, lane = tid & 63;
    int wm = (w >> 1) * 64, wn = (w & 1) * 64;
    int lrow = lane & 15, khalf = lane >> 4;

    floatx4 acc[4][4] = {};
    float ssA[4] = {0,0,0,0}, ssB[4] = {0,0,0,0};

    for (int kt = 0; kt < DIM/32; ++kt) {
        int k0 = kt * 32;
        float4 av[4], bv[4];
        #pragma unroll
        for (int h = 0; h < 4; ++h) {
            int f = tid + h*256;
            int row = f >> 3, c4 = (f & 7) * 4;
            av[h] = *(const float4*)(vb + (long)(m0+row)*DIM + k0 + c4);
            bv[h] = *(const float4*)(tb + (long)(n0+row)*DIM + k0 + c4);
            ssA[h] += av[h].x*av[h].x + av[h].y*av[h].y + av[h].z*av[h].z + av[h].w*av[h].w;
            ssB[h] += bv[h].x*bv[h].x + bv[h].y*bv[h].y + bv[h].z*bv[h].z + bv[h].w*bv[h].w;
        }
        __syncthreads();
        #pragma unroll
        for (int h = 0; h < 4; ++h) {
            int f = tid + h*256;
            int row = f >> 3, c4 = (f & 7) * 4;
            ushort4 ua = { f2bf(av[h].x), f2bf(av[h].y), f2bf(av[h].z), f2bf(av[h].w) };
            ushort4 ub = { f2bf(bv[h].x), f2bf(bv[h].y), f2bf(bv[h].z), f2bf(bv[h].w) };
            *(ushort4*)&As[row*40 + c4] = ua;
            *(ushort4*)&Bs[row*40 + c4] = ub;
        }
        __syncthreads();
        short8 af[4], bf[4];
        #pragma unroll
        for (int mi = 0; mi < 4; ++mi)
            af[mi] = *(const short8*)&As[(wm + mi*16 + lrow)*40 + khalf*8];
        #pragma unroll
        for (int nj = 0; nj < 4; ++nj)
            bf[nj] = *(const short8*)&Bs[(wn + nj*16 + lrow)*40 + khalf*8];
        #pragma unroll
        for (int mi = 0; mi < 4; ++mi)
            #pragma unroll
            for (int nj = 0; nj < 4; ++nj)
                acc[mi][nj] = __builtin_amdgcn_mfma_f32_16x16x32_bf16(
                                  af[mi], bf[nj], acc[mi][nj], 0, 0, 0);
        __syncthreads();
    }

    // row-norm reduce: 8 threads (tid&7) share each row
    #pragma unroll
    for (int h = 0; h < 4; ++h) {
        float sa = ssA[h], sb = ssB[h];
        #pragma unroll
        for (int off = 1; off < 8; off <<= 1) {
            sa += __shfl_xor(sa, off);
            sb += __shfl_xor(sb, off);
        }
        if ((tid & 7) == 0) {
            int r = (tid >> 3) + 32*h;
            invA[r] = 1.0f / fmaxf(sqrtf(sa), 1e-12f);
            invB[r] = SCALE_B / fmaxf(sqrtf(sb), 1e-12f);
        }
    }
    __syncthreads();

    __half* Kb = K + (long)bt * KBATCH_H;
    int col = lane & 15, rq = lane >> 4;          // C/D: col=lane&15, row=(lane>>4)*4+r
    #pragma unroll
    for (int nj = 0; nj < 4; ++nj) {
        int gnl = wn + nj*16 + col;
        float sn = invB[gnl];
        #pragma unroll
        for (int mi = 0; mi < 4; ++mi) {
            #pragma unroll
            for (int r = 0; r < 4; ++r) {
                int gml = wm + mi*16 + rq*4 + r;
                float val = acc[mi][nj][r] * invA[gml] * sn;
                Kb[(long)(m0+gml)*KP_H + (n0+gnl)] = __float2half(val);
            }
        }
    }
}

// ---------------- fused Sinkhorn (5 iters) + T*/loss/w outputs ----------------
// One 1024-thread block per batch; K2 L2-resident; aug row/col handled analytically.
__global__ __launch_bounds__(1024) void sinkhorn_kernel(
        const __half* __restrict__ K,
        const int* __restrict__ lenvp, const int* __restrict__ lentp,
        float* __restrict__ loss_out, float* __restrict__ out_wv,
        float* __restrict__ out_wt) {
    int bid = blockIdx.x;
    int bt = ((bid & 7) << 3) + (bid >> 3);       // match GEMM's batch->XCD mapping
    int lenv = lenvp[bt], lent = lentp[bt];
    const __half* Kb = K + (long)bt * KBATCH_H;
    int tid = threadIdx.x, w = tid >> 6, lane = tid & 63;

    __shared__ float u2[512], vv2[512];
    __shared__ float mp[2][8][64], sp[2][8][64];
    __shared__ float wv[512], ct[512];
    __shared__ float sc[8];    // 0:u_aug 1:u_m 2:vv_aug 3:vv_m 4:Sru 5:Srv 6:denv 7:dent
    __shared__ float lw[16];

    float lmu2 = lg2(1.0f/((float)lenv + 1e-9f) + 1e-9f);
    float lnu2 = lg2(1.0f/((float)lent + 1e-9f) + 1e-9f);

    if (tid < 512) { vv2[tid] = 0.0f; ct[tid] = 0.0f; }
    if (tid < 8) sc[tid] = 0.0f;
    __syncthreads();

    for (int it = 0; it < 5; ++it) {
        // ---------- ROW phase: u from old vv ----------
        float vv_aug = sc[2], vv_m = sc[3];
        float auga = LOG2E + vv_aug;
        for (int i = w; i < lenv; i += 16) {
            const __half* Krow = Kb + (long)i * KP_H;
            float x[8];
            #pragma unroll
            for (int c = 0; c < 4; ++c) {
                int j0 = c*128 + lane*2;
                __half2 h2 = *(const __half2*)(Krow + j0);
                x[2*c]   = (j0   < lent) ? __low2float(h2)  + vv2[j0]   : NEGI;
                x[2*c+1] = (j0+1 < lent) ? __high2float(h2) + vv2[j0+1] : NEGI;
            }
            float m = fmaxf(fmaxf(fmaxf(x[0],x[1]),fmaxf(x[2],x[3])),
                            fmaxf(fmaxf(x[4],x[5]),fmaxf(x[6],x[7])));
            float s = 0.f;
            #pragma unroll
            for (int q = 0; q < 8; ++q) s += ex2(x[q] - m);
            #pragma unroll
            for (int off = 32; off; off >>= 1) {
                float m2 = __shfl_xor(m, off), s2 = __shfl_xor(s, off);
                float tm = fmaxf(m, m2);
                s = s*ex2(m - tm) + s2*ex2(m2 - tm);
                m = tm;
            }
            float tm = fmaxf(m, auga);
            s = s*ex2(m - tm) + ex2(auga - tm);
            if (lane == 0) u2[i] = lmu2 - (tm + lg2(s));
        }
        if (w == 15) {      // u_aug = -(G + LSE(all vv)), u_m = LM9 - G - vv_aug
            float x[8];
            #pragma unroll
            for (int c = 0; c < 8; ++c) {
                int j = lane + 64*c;
                x[c] = (j < lent) ? vv2[j] : NEGI;
            }
            float m = fmaxf(fmaxf(fmaxf(x[0],x[1]),fmaxf(x[2],x[3])),
                            fmaxf(fmaxf(x[4],x[5]),fmaxf(x[6],x[7])));
            float s = 0.f;
            #pragma unroll
            for (int q = 0; q < 8; ++q) s += ex2(x[q] - m);
            #pragma unroll
            for (int off = 32; off; off >>= 1) {
                float m2 = __shfl_xor(m, off), s2 = __shfl_xor(s, off);
                float tm = fmaxf(m, m2);
                s = s*ex2(m - tm) + s2*ex2(m2 - tm);
                m = tm;
            }
            float cnt = (float)(512 - lent);
            float tm = fmaxf(m, vv_m);
            s = s*ex2(m - tm) + cnt*ex2(vv_m - tm);
            m = tm;
            tm = fmaxf(m, vv_aug);
            s = s*ex2(m - tm) + ex2(vv_aug - tm);
            if (lane == 0) {
                sc[0] = -(LOG2E + tm + lg2(s));
                sc[1] = LM9_2 - LOG2E - vv_aug;
            }
        }
        __syncthreads();

        // ---------- COL phase part 1: per-(half,col) partial LSE over rows ----------
        {
            int grp = w & 7, half = w >> 3;
            int j = grp*64 + lane;
            int hl = (lenv + 1) >> 1;
            int i0 = half*hl, i1 = min(lenv, i0 + hl);
            float m = NEGI, s = 0.f;
            if (j < lent) {
                const __half* p = Kb + (long)i0 * KP_H + j;
                int i = i0;
                for (; i + 8 <= i1; i += 8) {
                    float x[8];
                    #pragma unroll
                    for (int q = 0; q < 8; ++q)
                        x[q] = __half2float(p[(long)q*KP_H]) + u2[i+q];
                    float cm = fmaxf(fmaxf(fmaxf(x[0],x[1]),fmaxf(x[2],x[3])),
                                     fmaxf(fmaxf(x[4],x[5]),fmaxf(x[6],x[7])));
                    float nm = fmaxf(m, cm);
                    float cs = 0.f;
                    #pragma unroll
                    for (int q = 0; q < 8; ++q) cs += ex2(x[q] - nm);
                    s = s*ex2(m - nm) + cs;
                    m = nm;
                    p += 8*KP_H;
                }
                for (; i < i1; ++i) {
                    float x = __half2float(*p) + u2[i];
                    float nm = fmaxf(m, x);
                    s = s*ex2(m - nm) + ex2(x - nm);
                    m = nm;
                    p += KP_H;
                }
            }
            mp[half][grp][lane] = m; sp[half][grp][lane] = s;
        }
        __syncthreads();

        // ---------- COL phase part 2: merge + new vv scalars ----------
        float u_aug = sc[0], u_m = sc[1];
        if (w < 8) {
            int j2 = w*64 + lane;
            if (j2 < lent) {
                float M = mp[0][w][lane], S = sp[0][w][lane];
                float m2 = mp[1][w][lane], s2 = sp[1][w][lane];
                float tm = fmaxf(M, m2);
                S = S*ex2(M - tm) + s2*ex2(m2 - tm);
                M = tm;
                float a = LOG2E + u_aug;
                tm = fmaxf(M, a);
                S = S*ex2(M - tm) + ex2(a - tm);
                vv2[j2] = lnu2 - (tm + lg2(S));
            }
        } else if (w == 8) {    // vv_aug = -(G + LSE(all u)), vv_m = LM9 - G - u_aug
            float x[8];
            #pragma unroll
            for (int c = 0; c < 8; ++c) {
                int i = lane + 64*c;
                x[c] = (i < lenv) ? u2[i] : NEGI;
            }
            float m = fmaxf(fmaxf(fmaxf(x[0],x[1]),fmaxf(x[2],x[3])),
                            fmaxf(fmaxf(x[4],x[5]),fmaxf(x[6],x[7])));
            float s = 0.f;
            #pragma unroll
            for (int q = 0; q < 8; ++q) s += ex2(x[q] - m);
            #pragma unroll
            for (int off = 32; off; off >>= 1) {
                float m2 = __shfl_xor(m, off), s2 = __shfl_xor(s, off);
                float tm = fmaxf(m, m2);
                s = s*ex2(m - tm) + s2*ex2(m2 - tm);
                m = tm;
            }
            float cnt = (float)(512 - lenv);
            float tm = fmaxf(m, u_m);
            s = s*ex2(m - tm) + cnt*ex2(u_m - tm);
            m = tm;
            tm = fmaxf(m, u_aug);
            s = s*ex2(m - tm) + ex2(u_aug - tm);
            if (lane == 0) {
                sc[2] = -(LOG2E + tm + lg2(s));
                sc[3] = LM9_2 - LOG2E - u_aug;
            }
        }
        __syncthreads();
    }

    // ---------- FINAL: T*, loss, row/col relu-sums, outputs ----------
    float u_aug = sc[0], u_m = sc[1], vv_aug = sc[2], vv_m = sc[3];
    float lossacc = 0.f;
    float cs[8] = {0,0,0,0,0,0,0,0};
    for (int i = w; i < lenv; i += 16) {
        float ui = u2[i];
        const __half* Krow = Kb + (long)i * KP_H;
        float rowacc = 0.f;
        #pragma unroll
        for (int c = 0; c < 4; ++c) {
            int j0 = c*128 + lane*2;
            __half2 h2 = *(const __half2*)(Krow + j0);
            float k0 = __low2float(h2), k1 = __high2float(h2);
            float t0 = (j0   < lent) ? ex2(ui + vv2[j0]   + k0) : 0.f;
            float t1 = (j0+1 < lent) ? ex2(ui + vv2[j0+1] + k1) : 0.f;
            lossacc += t0*(1.f - C_EPS*k0) + t1*(1.f - C_EPS*k1);
            float th0 = fmaxf(t0 - TAU_OT, 0.f);
            float th1 = fmaxf(t1 - TAU_OT, 0.f);
            rowacc += th0 + th1;
            cs[2*c] += th0; cs[2*c+1] += th1;
        }
        #pragma unroll
        for (int off = 32; off; off >>= 1) rowacc += __shfl_xor(rowacc, off);
        if (lane == 0) wv[i] = rowacc;
    }
    #pragma unroll
    for (int c = 0; c < 4; ++c) {
        atomicAdd(&ct[c*128 + lane*2    ], cs[2*c]);
        atomicAdd(&ct[c*128 + lane*2 + 1], cs[2*c+1]);
    }
    #pragma unroll
    for (int off = 32; off; off >>= 1) lossacc += __shfl_xor(lossacc, off);
    if (lane == 0) lw[w] = lossacc;
    __syncthreads();

    if (w == 0) {               // Sru = sum exp2(u2)
        float s = 0.f;
        #pragma unroll
        for (int c = 0; c < 8; ++c) { int i = lane + 64*c; if (i < lenv) s += ex2(u2[i]); }
        #pragma unroll
        for (int off = 32; off; off >>= 1) s += __shfl_xor(s, off);
        if (lane == 0) sc[4] = s;
    } else if (w == 1) {        // Srv = sum exp2(vv2)
        float s = 0.f;
        #pragma unroll
        for (int c = 0; c < 8; ++c) { int j = lane + 64*c; if (j < lent) s += ex2(vv2[j]); }
        #pragma unroll
        for (int off = 32; off; off >>= 1) s += __shfl_xor(s, off);
        if (lane == 0) sc[5] = s;
    } else if (w == 2) {        // denom_v
        float s = 0.f;
        #pragma unroll
        for (int c = 0; c < 8; ++c) { int i = lane + 64*c; if (i < lenv) s += wv[i]; }
        #pragma unroll
        for (int off = 32; off; off >>= 1) s += __shfl_xor(s, off);
        if (lane == 0) sc[6] = s + 512.0f*DELTA_OT;
    } else if (w == 3) {        // denom_t
        float s = 0.f;
        #pragma unroll
        for (int c = 0; c < 8; ++c) { int j = lane + 64*c; s += ct[j]; }
        #pragma unroll
        for (int off = 32; off; off >>= 1) s += __shfl_xor(s, off);
        if (lane == 0) sc[7] = s + 512.0f*DELTA_OT;
    }
    __syncthreads();

    if (tid == 0) {
        float l = 0.f;
        #pragma unroll
        for (int q = 0; q < 16; ++q) l += lw[q];
        float Sru = sc[4], Srv = sc[5];
        float e1 = ex2(LOG2E);          // = e
        float laug = 0.9f * e1 * ( ex2(vv_aug)*(Sru + (float)(512 - lenv)*ex2(u_m))
                                 + ex2(u_aug)*(Srv + (float)(512 - lent)*ex2(vv_m))
                                 + ex2(u_aug + vv_aug) );
        loss_out[bt] = l + laug;
    }
    float denv = sc[6], dent = sc[7];
    if (tid < 512) {
        float nv = ((tid < lenv) ? wv[tid] : 0.f) + DELTA_OT;
        out_wv[(long)bt*512 + tid] = nv / denv;
        float nt2 = ct[tid] + DELTA_OT;
        out_wt[(long)bt*512 + tid] = nt2 / dent;
    }
}

// ---------------- loss mean over batches ----------------
__global__ void loss_reduce(const float* __restrict__ loss, float* __restrict__ out) {
    float s = loss[threadIdx.x];
    #pragma unroll
    for (int off = 32; off; off >>= 1) s += __shfl_xor(s, off);
    if (threadIdx.x == 0) out[0] = s * (1.0f/64.0f);
}

// ---------------- launch ----------------
extern "C" void kernel_launch(void* const* d_in, const int* in_sizes, int n_in,
                              void* d_out, int out_size, void* d_ws, size_t ws_size,
                              hipStream_t stream) {
    const float* v = (const float*)d_in[0];
    const float* t = (const float*)d_in[1];
    const unsigned char* vm = (const unsigned char*)d_in[2];
    const unsigned char* tm = (const unsigned char*)d_in[3];
    float* ws  = (float*)d_ws;
    float* out = (float*)d_out;

    int*   LENV = (int*)(ws + OFF_LENV);
    int*   LENT = (int*)(ws + OFF_LENT);
    float* LOSS = ws + OFF_LOSS;
    __half* Kmat = (__half*)(ws + OFF_KH);

    len_kernel<<<dim3(BB, 2), 512, 0, stream>>>(vm, tm, LENV, LENT);
    gemm_kernel<<<dim3(1024), 256, 0, stream>>>(v, t, LENV, LENT, Kmat);
    sinkhorn_kernel<<<dim3(BB), 1024, 0, stream>>>(Kmat, LENV, LENT, LOSS,
                                                   out + 1, out + 1 + (long)BB*512);
    loss_reduce<<<1, 64, 0, stream>>>(LOSS, out);
}

// Round 4
// 378.826 us; speedup vs baseline: 1.6003x; 1.6003x over previous
//
#include <hip/hip_runtime.h>
#include <hip/hip_fp16.h>

// ---------------- problem constants ----------------
#define TAU_OT   0.005f
#define DELTA_OT 1e-9f
#define LOG2E    1.4426950408889634f
#define C_EPS    0.06931471805599453f   /* 0.1*ln2 : (1 - eps*K_nat) = 1 - C_EPS*K2 */
#define LM9_2    -29.897352853986263f   /* log2(1e-9) */
#define NEGI     -1.0e30f
#define SCALE_B  14.426950408889634f    /* INV_EPS * LOG2E folded into B norms */

constexpr int BB  = 64;
constexpr int DIM = 768;
constexpr int KP_H = 520;                     // K row pitch in halves (1040 B)
constexpr long KB_H = (long)512 * KP_H;       // per-batch K

// ---------------- workspace layout (float units) ----------------
constexpr size_t OFF_LENV = 0;                 // 64 int
constexpr size_t OFF_LENT = 64;                // 64 int
constexpr size_t OFF_SCAL = 128;               // 64*4: u_aug,u_m,vv_aug,vv_m
constexpr size_t OFF_LOSSA= 384;               // 64
constexpr size_t OFF_SRU  = 448;               // 64
constexpr size_t OFF_SRV  = 512;               // 64
constexpr size_t OFF_U    = 576;               // 64*512
constexpr size_t OFF_VV   = OFF_U   + 32768;   // 64*512
constexpr size_t OFF_WVA  = OFF_VV  + 32768;   // 64*512
constexpr size_t OFF_WTA  = OFF_WVA + 32768;   // 64*512
constexpr size_t OFF_KH   = OFF_WTA + 32768;   // half[64*512*520]

typedef __attribute__((ext_vector_type(8))) short short8;
typedef __attribute__((ext_vector_type(4))) float floatx4;

__device__ inline float ex2(float x){ float r; asm("v_exp_f32 %0, %1" : "=v"(r) : "v"(x)); return r; }
__device__ inline float lg2(float x){ float r; asm("v_log_f32 %0, %1" : "=v"(r) : "v"(x)); return r; }
__device__ inline unsigned cvtpk(float a, float b){
    unsigned r; asm("v_cvt_pk_bf16_f32 %0, %1, %2" : "=v"(r) : "v"(a), "v"(b)); return r;
}

// ---------------- mask dtype detection ----------------
__device__ inline int detect_mode(const unsigned char* p) {
    unsigned char b0 = p[0], b1 = p[1];
    if (b0 == 0) return 2;          // float32
    return (b1 != 0) ? 0 : 1;       // 0: u8/bool, 1: int32
}
__device__ inline int read_mask(const unsigned char* p, long idx, int mode) {
    if (mode == 0) return p[idx] != 0;
    if (mode == 1) return p[4*idx] != 0;
    return ((const float*)p)[idx] != 0.0f;
}

// batch <-> block mapping: batch b's blocks all land on XCD (b>>3)
__device__ inline void map_bs(int bid, int& b, int& s) {
    b = (bid & 7) * 8 + ((bid >> 3) & 7);
    s = bid >> 6;
}

// ---------------- lengths + init (no memset needed) ----------------
__global__ void len_init(const unsigned char* vm, const unsigned char* tm,
                         int* LENV, int* LENT, float* VV, float* SCAL,
                         float* WTA, float* LOSSA, float* SRU) {
    int b = blockIdx.x;
    bool isV = (blockIdx.y == 0);
    const unsigned char* p = isV ? vm : tm;
    int mode = detect_mode(p);
    int i = threadIdx.x;                       // 512 threads
    float s = (float)read_mask(p, (long)b*512 + i, mode);
    #pragma unroll
    for (int off = 32; off; off >>= 1) s += __shfl_xor(s, off);
    __shared__ float wsum[8];
    int w = i >> 6, lane = i & 63;
    if (lane == 0) wsum[w] = s;
    __syncthreads();
    float len = 0.f;
    #pragma unroll
    for (int q = 0; q < 8; ++q) len += wsum[q];
    int ln = (int)(len + 0.5f);
    if (isV) {
        if (i == 0) {
            LENV[b] = ln;
            SCAL[b*4+2] = 0.f; SCAL[b*4+3] = 0.f;   // vv_aug, vv_m init
            LOSSA[b] = 0.f; SRU[b] = 0.f;
        }
    } else {
        if (i == 0) LENT[b] = ln;
        VV[b*512 + i] = (i < ln) ? 0.f : NEGI;       // exp2(NEGI)=0 kills masked cols
        WTA[b*512 + i] = 0.f;
    }
}

// ---------------- bf16 MFMA batched GEMM -> K2 (fp16, *10*log2e) ----------------
__global__ __launch_bounds__(256) void gemm_kernel(const float* __restrict__ v,
        const float* __restrict__ t,
        const int* __restrict__ lenvp, const int* __restrict__ lentp,
        __half* __restrict__ K) {
    int bid = blockIdx.x;
    int xcd = bid & 7, kk = bid >> 3;
    int bt   = xcd * 8 + (kk >> 4);
    int tile = kk & 15;
    int m0 = (tile >> 2) * 128, n0 = (tile & 3) * 128;
    if (m0 >= lenvp[bt] || n0 >= lentp[bt]) return;   // fully-masked tile

    __shared__ ushort As[128*40];
    __shared__ ushort Bs[128*40];
    __shared__ float invA[128], invB[128];
    const float* vb = v + (long)bt * 512 * DIM;
    const float* tb = t + (long)bt * 512 * DIM;
    int tid = threadIdx.x;
    int w = tid >> 6, lane = tid & 63;
    int wm = (w >> 1) * 64, wn = (w & 1) * 64;
    int lrow = lane & 15, khalf = lane >> 4;

    floatx4 acc[4][4] = {};
    float ssA[4] = {0,0,0,0}, ssB[4] = {0,0,0,0};

    for (int kt = 0; kt < DIM/32; ++kt) {
        int k0 = kt * 32;
        float4 av[4], bv[4];
        #pragma unroll
        for (int h = 0; h < 4; ++h) {
            int f = tid + h*256;
            int row = f >> 3, c4 = (f & 7) * 4;
            av[h] = *(const float4*)(vb + (long)(m0+row)*DIM + k0 + c4);
            bv[h] = *(const float4*)(tb + (long)(n0+row)*DIM + k0 + c4);
            ssA[h] += av[h].x*av[h].x + av[h].y*av[h].y + av[h].z*av[h].z + av[h].w*av[h].w;
            ssB[h] += bv[h].x*bv[h].x + bv[h].y*bv[h].y + bv[h].z*bv[h].z + bv[h].w*bv[h].w;
        }
        __syncthreads();
        #pragma unroll
        for (int h = 0; h < 4; ++h) {
            int f = tid + h*256;
            int row = f >> 3, c4 = (f & 7) * 4;
            uint2 ua = { cvtpk(av[h].x, av[h].y), cvtpk(av[h].z, av[h].w) };
            uint2 ub = { cvtpk(bv[h].x, bv[h].y), cvtpk(bv[h].z, bv[h].w) };
            *(uint2*)&As[row*40 + c4] = ua;
            *(uint2*)&Bs[row*40 + c4] = ub;
        }
        __syncthreads();
        short8 af[4], bf[4];
        #pragma unroll
        for (int mi = 0; mi < 4; ++mi)
            af[mi] = *(const short8*)&As[(wm + mi*16 + lrow)*40 + khalf*8];
        #pragma unroll
        for (int nj = 0; nj < 4; ++nj)
            bf[nj] = *(const short8*)&Bs[(wn + nj*16 + lrow)*40 + khalf*8];
        #pragma unroll
        for (int mi = 0; mi < 4; ++mi)
            #pragma unroll
            for (int nj = 0; nj < 4; ++nj)
                acc[mi][nj] = __builtin_amdgcn_mfma_f32_16x16x32_bf16(
                                  af[mi], bf[nj], acc[mi][nj], 0, 0, 0);
        __syncthreads();
    }

    #pragma unroll
    for (int h = 0; h < 4; ++h) {
        float sa = ssA[h], sb = ssB[h];
        #pragma unroll
        for (int off = 1; off < 8; off <<= 1) {
            sa += __shfl_xor(sa, off);
            sb += __shfl_xor(sb, off);
        }
        if ((tid & 7) == 0) {
            int r = (tid >> 3) + 32*h;
            invA[r] = 1.0f / fmaxf(sqrtf(sa), 1e-12f);
            invB[r] = SCALE_B / fmaxf(sqrtf(sb), 1e-12f);
        }
    }
    __syncthreads();

    __half* Kb = K + (long)bt * KB_H;
    int col = lane & 15, rq = lane >> 4;
    #pragma unroll
    for (int nj = 0; nj < 4; ++nj) {
        int gnl = wn + nj*16 + col;
        float sn = invB[gnl];
        #pragma unroll
        for (int mi = 0; mi < 4; ++mi) {
            #pragma unroll
            for (int r = 0; r < 4; ++r) {
                int gml = wm + mi*16 + rq*4 + r;
                float val = acc[mi][nj][r] * invA[gml] * sn;
                Kb[(long)(m0+gml)*KP_H + (n0+gnl)] = __float2half(val);
            }
        }
    }
}

// ---------------- Sinkhorn row pass: u = lmu - lg2(sum_j 2^(K+vv) + 2^auga) ----------------
__global__ __launch_bounds__(256) void row_kernel(const __half* __restrict__ K,
        const float* __restrict__ VV, float* __restrict__ U, float* __restrict__ SCAL,
        const int* __restrict__ LENV, const int* __restrict__ LENT) {
    int b, s; map_bs(blockIdx.x, b, s);
    int lenv = LENV[b], lent = LENT[b];
    __shared__ float vvs[512];
    int tid = threadIdx.x;
    *(float2*)&vvs[tid*2] = *(const float2*)&VV[b*512 + tid*2];
    float vv_aug = SCAL[b*4+2], vv_m = SCAL[b*4+3];
    __syncthreads();
    int w = tid >> 6, lane = tid & 63;
    int base = s*64 + w*16;
    float lmu2 = lg2(1.0f/((float)lenv + 1e-9f) + 1e-9f);
    float ea = ex2(LOG2E + vv_aug);
    const __half* Kb = K + (long)b * KB_H;
    int nr = min(16, max(0, lenv - base));
    #pragma unroll 2
    for (int r = 0; r < nr; ++r) {
        int i = base + r;
        const __half2* Kr = (const __half2*)(Kb + (long)i * KP_H);
        float ss = 0.f;
        #pragma unroll
        for (int c = 0; c < 4; ++c) {
            __half2 h2 = Kr[c*64 + lane];
            int j0 = c*128 + lane*2;
            ss += ex2(__low2float(h2) + vvs[j0]) + ex2(__high2float(h2) + vvs[j0+1]);
        }
        #pragma unroll
        for (int off = 32; off; off >>= 1) ss += __shfl_xor(ss, off);
        if (lane == 0) U[b*512 + i] = lmu2 - lg2(ss + ea);
    }
    if (lane == 0)
        for (int r = nr; r < 16; ++r) U[b*512 + base + r] = NEGI;
    if (s == 0 && w == 3) {           // u_aug, u_m for the col pass
        float sv = 0.f;
        #pragma unroll
        for (int c = 0; c < 8; ++c) sv += ex2(vvs[c*64 + lane]);
        #pragma unroll
        for (int off = 32; off; off >>= 1) sv += __shfl_xor(sv, off);
        if (lane == 0) {
            float tot = sv + (float)(512 - lent)*ex2(vv_m) + ex2(vv_aug);
            SCAL[b*4+0] = -(LOG2E + lg2(tot));
            SCAL[b*4+1] = LM9_2 - LOG2E - vv_aug;
        }
    }
}

// ---------------- Sinkhorn col pass: vv = lnu - lg2(sum_i 2^(K+u) + 2^(1.44+u_aug)) ----------------
__global__ __launch_bounds__(256) void col_kernel(const __half* __restrict__ K,
        const float* __restrict__ U, float* __restrict__ VV, float* __restrict__ SCAL,
        const int* __restrict__ LENV, const int* __restrict__ LENT) {
    int b, s; map_bs(blockIdx.x, b, s);
    int lenv = LENV[b], lent = LENT[b];
    __shared__ float us[512];
    __shared__ float part[4][64];
    int tid = threadIdx.x;
    *(float2*)&us[tid*2] = *(const float2*)&U[b*512 + tid*2];
    float u_aug = SCAL[b*4+0], u_m = SCAL[b*4+1];
    __syncthreads();
    int w = tid >> 6, lane = tid & 63;
    int j = s*64 + lane;
    int chunk = ((lenv + 31) >> 5) << 3;       // lenv/4 rounded up to mult of 8
    int i0 = w*chunk, i1 = min(lenv, i0 + chunk);
    const __half* p = K + (long)b*KB_H + (long)i0*KP_H + j;
    float acc = 0.f;
    int i = i0;
    for (; i + 8 <= i1; i += 8) {
        float x[8];
        #pragma unroll
        for (int q = 0; q < 8; ++q) x[q] = __half2float(p[(long)q*KP_H]) + us[i+q];
        #pragma unroll
        for (int q = 0; q < 8; ++q) acc += ex2(x[q]);
        p += 8*KP_H;
    }
    for (; i < i1; ++i) { acc += ex2(__half2float(*p) + us[i]); p += KP_H; }
    part[w][lane] = acc;
    __syncthreads();
    if (w == 0) {
        float tot = part[0][lane] + part[1][lane] + part[2][lane] + part[3][lane]
                  + ex2(LOG2E + u_aug);
        float lnu2 = lg2(1.0f/((float)lent + 1e-9f) + 1e-9f);
        VV[b*512 + j] = (j < lent) ? (lnu2 - lg2(tot)) : NEGI;
    } else if (w == 1 && s == 0) {    // vv_aug, vv_m for the next row pass
        float su = 0.f;
        #pragma unroll
        for (int c = 0; c < 8; ++c) su += ex2(us[c*64 + lane]);
        #pragma unroll
        for (int off = 32; off; off >>= 1) su += __shfl_xor(su, off);
        if (lane == 0) {
            float tot = su + (float)(512 - lenv)*ex2(u_m) + ex2(u_aug);
            SCAL[b*4+2] = -(LOG2E + lg2(tot));
            SCAL[b*4+3] = LM9_2 - LOG2E - u_aug;
        }
    }
}

// ---------------- final: T*, loss, row/col relu-sums ----------------
__global__ __launch_bounds__(256) void final_partial(const __half* __restrict__ K,
        const float* __restrict__ U, const float* __restrict__ VV,
        float* __restrict__ WVA, float* __restrict__ WTA,
        float* __restrict__ LOSSA, float* __restrict__ SRU, float* __restrict__ SRV,
        const int* __restrict__ LENV) {
    int b, s; map_bs(blockIdx.x, b, s);
    int lenv = LENV[b];
    __shared__ float vvs[512];
    __shared__ float colsum[512];
    __shared__ float lw[4];
    int tid = threadIdx.x;
    *(float2*)&vvs[tid*2] = *(const float2*)&VV[b*512 + tid*2];
    colsum[tid] = 0.f; colsum[tid+256] = 0.f;
    __syncthreads();
    int w = tid >> 6, lane = tid & 63;
    int base = s*64 + w*16;
    const __half* Kb = K + (long)b * KB_H;
    float creg[8] = {0,0,0,0,0,0,0,0};
    float lossacc = 0.f;
    int nr = min(16, max(0, lenv - base));
    for (int r = 0; r < nr; ++r) {
        int i = base + r;
        float ui = U[b*512 + i];
        const __half2* Kr = (const __half2*)(Kb + (long)i * KP_H);
        float rowacc = 0.f;
        #pragma unroll
        for (int c = 0; c < 4; ++c) {
            __half2 h2 = Kr[c*64 + lane];
            int j0 = c*128 + lane*2;
            float k0 = __low2float(h2), k1 = __high2float(h2);
            float t0 = ex2(ui + vvs[j0]   + k0);
            float t1 = ex2(ui + vvs[j0+1] + k1);
            lossacc += t0*(1.f - C_EPS*k0) + t1*(1.f - C_EPS*k1);
            float th0 = fmaxf(t0 - TAU_OT, 0.f), th1 = fmaxf(t1 - TAU_OT, 0.f);
            rowacc += th0 + th1;
            creg[2*c] += th0; creg[2*c+1] += th1;
        }
        #pragma unroll
        for (int off = 32; off; off >>= 1) rowacc += __shfl_xor(rowacc, off);
        if (lane == 0) WVA[b*512 + i] = rowacc;
    }
    if (lane == 0)
        for (int r = nr; r < 16; ++r) WVA[b*512 + base + r] = 0.f;
    #pragma unroll
    for (int c = 0; c < 4; ++c) {
        atomicAdd(&colsum[c*128 + lane*2    ], creg[2*c]);
        atomicAdd(&colsum[c*128 + lane*2 + 1], creg[2*c+1]);
    }
    #pragma unroll
    for (int off = 32; off; off >>= 1) lossacc += __shfl_xor(lossacc, off);
    if (lane == 0) lw[w] = lossacc;
    // Sru partial over this block's 64 rows (masked rows: exp2(NEGI)=0)
    if (w == 1) {
        float e = ex2(U[b*512 + s*64 + lane]);
        #pragma unroll
        for (int off = 32; off; off >>= 1) e += __shfl_xor(e, off);
        if (lane == 0) atomicAdd(&SRU[b], e);
    }
    if (w == 2 && s == 0) {
        float sv = 0.f;
        #pragma unroll
        for (int c = 0; c < 8; ++c) sv += ex2(vvs[c*64 + lane]);
        #pragma unroll
        for (int off = 32; off; off >>= 1) sv += __shfl_xor(sv, off);
        if (lane == 0) SRV[b] = sv;
    }
    __syncthreads();
    atomicAdd(&WTA[b*512 + tid],       colsum[tid]);
    atomicAdd(&WTA[b*512 + tid + 256], colsum[tid + 256]);
    if (tid == 0) atomicAdd(&LOSSA[b], lw[0]+lw[1]+lw[2]+lw[3]);
}

// ---------------- normalize w vectors ----------------
__global__ void wnorm_kernel(const float* __restrict__ num, float* __restrict__ out) {
    int b = blockIdx.x;
    float v = num[b*512 + threadIdx.x] + DELTA_OT;
    float s = v;
    #pragma unroll
    for (int off = 32; off; off >>= 1) s += __shfl_xor(s, off);
    __shared__ float wsum[8];
    int w = threadIdx.x >> 6, lane = threadIdx.x & 63;
    if (lane == 0) wsum[w] = s;
    __syncthreads();
    float tot = 0.f;
    #pragma unroll
    for (int q = 0; q < 8; ++q) tot += wsum[q];
    out[b*512 + threadIdx.x] = v / tot;
}

// ---------------- loss: aug terms + mean ----------------
__global__ void loss_final(const float* __restrict__ LOSSA, const float* __restrict__ SRU,
        const float* __restrict__ SRV, const float* __restrict__ SCAL,
        const int* __restrict__ LENV, const int* __restrict__ LENT,
        float* __restrict__ out) {
    int b = threadIdx.x;
    float u_aug = SCAL[b*4+0], u_m = SCAL[b*4+1];
    float vv_aug = SCAL[b*4+2], vv_m = SCAL[b*4+3];
    float lenv = (float)LENV[b], lent = (float)LENT[b];
    float laug = 0.9f * ( ex2(vv_aug + LOG2E) * (SRU[b] + (512.f - lenv)*ex2(u_m))
                        + ex2(u_aug  + LOG2E) * (SRV[b] + (512.f - lent)*ex2(vv_m))
                        + ex2(u_aug + vv_aug + LOG2E) );
    float tot = LOSSA[b] + laug;
    #pragma unroll
    for (int off = 32; off; off >>= 1) tot += __shfl_xor(tot, off);
    if (b == 0) out[0] = tot * (1.0f/64.0f);
}

// ---------------- launch ----------------
extern "C" void kernel_launch(void* const* d_in, const int* in_sizes, int n_in,
                              void* d_out, int out_size, void* d_ws, size_t ws_size,
                              hipStream_t stream) {
    const float* v = (const float*)d_in[0];
    const float* t = (const float*)d_in[1];
    const unsigned char* vm = (const unsigned char*)d_in[2];
    const unsigned char* tm = (const unsigned char*)d_in[3];
    float* ws  = (float*)d_ws;
    float* out = (float*)d_out;

    int*   LENV = (int*)(ws + OFF_LENV);
    int*   LENT = (int*)(ws + OFF_LENT);
    float* SCAL = ws + OFF_SCAL;
    float* LOSSA= ws + OFF_LOSSA;
    float* SRU  = ws + OFF_SRU;
    float* SRV  = ws + OFF_SRV;
    float* U    = ws + OFF_U;
    float* VV   = ws + OFF_VV;
    float* WVA  = ws + OFF_WVA;
    float* WTA  = ws + OFF_WTA;
    __half* Kmat = (__half*)(ws + OFF_KH);

    len_init<<<dim3(BB, 2), 512, 0, stream>>>(vm, tm, LENV, LENT, VV, SCAL, WTA, LOSSA, SRU);
    gemm_kernel<<<dim3(1024), 256, 0, stream>>>(v, t, LENV, LENT, Kmat);

    for (int it = 0; it < 5; ++it) {
        row_kernel<<<dim3(512), 256, 0, stream>>>(Kmat, VV, U, SCAL, LENV, LENT);
        col_kernel<<<dim3(512), 256, 0, stream>>>(Kmat, U, VV, SCAL, LENV, LENT);
    }

    final_partial<<<dim3(512), 256, 0, stream>>>(Kmat, U, VV, WVA, WTA, LOSSA, SRU, SRV, LENV);
    wnorm_kernel<<<BB, 512, 0, stream>>>(WVA, out + 1);
    wnorm_kernel<<<BB, 512, 0, stream>>>(WTA, out + 1 + (long)BB*512);
    loss_final<<<1, 64, 0, stream>>>(LOSSA, SRU, SRV, SCAL, LENV, LENT, out);
}